// Round 5
// baseline (880.169 us; speedup 1.0000x reference)
//
#include <hip/hip_runtime.h>

// GRU, T=4096, B=256, I=2, H=32, O=1.
// Only batch row 255 reaches the output -> compute only that row.
// Single-wave sequential recurrence; issue/latency-bound.
// R5: R4 but with the z-exchange reverted to __shfl_xor (known-good; R4's
//     v_permlane32_swap had an inverted half-swap convention -> r/z mixup,
//     absmax 2.2e-2). Keep: asm-pinned VGPR weights, SGPR h broadcast via
//     readlane, folded exp2 scales, transposed float4 h stores.

#define TT 4096

__device__ __forceinline__ float rl(float v, int l) {
    return __int_as_float(__builtin_amdgcn_readlane(__float_as_int(v), l));
}
__device__ __forceinline__ float fexp2(float x) { return __builtin_amdgcn_exp2f(x); }
__device__ __forceinline__ float frcp(float x)  { return __builtin_amdgcn_rcpf(x); }

#define NLOG2E  (-1.44269504088896340736f)   // r/z pre-activations pre-scaled
#define TLOG2E  ( 2.88539008177792681472f)   // n pre-activation pre-scaled

// One wave. Lane l owns w_hh gate-row l (r rows on lanes 0..31, z rows on
// lanes 32..63) and n-row 64+(l&31) (duplicated across halves -> both halves
// compute bitwise-identical h; no exec masks needed). h replicated: lane l
// holds h[l&31] in h_el; all 32 h values broadcast to SGPRs each step.
__global__ __launch_bounds__(64, 1)
__attribute__((amdgpu_waves_per_eu(1, 1)))
void gru_seq(const float* __restrict__ x,
             const float* __restrict__ w_ih,
             const float* __restrict__ w_hh,
             const float* __restrict__ b_ih,
             const float* __restrict__ b_hh,
             float* __restrict__ hbuf)
{
    const int lane = threadIdx.x;
    const int low  = lane & 31;
    const bool hi  = lane >= 32;
    const int row0 = lane;        // r/z row
    const int row1 = 64 + low;    // n row (both halves)

    float w0a[32], w1a[32];
#pragma unroll
    for (int j = 0; j < 32; ++j) w0a[j] = w_hh[row0 * 32 + j] * NLOG2E;
#pragma unroll
    for (int j = 0; j < 32; ++j) w1a[j] = w_hh[row1 * 32 + j] * TLOG2E;
    // Pin: asm results are not rematerializable -> weights stay in VGPRs
    // (R1-R3: RA kept rematerializing the weight loads; VGPR_Count stuck at 64).
#pragma unroll
    for (int j = 0; j < 32; ++j) asm("" : "+v"(w0a[j]));
#pragma unroll
    for (int j = 0; j < 32; ++j) asm("" : "+v"(w1a[j]));

    const float wi00 = w_ih[row0 * 2 + 0] * NLOG2E;
    const float wi01 = w_ih[row0 * 2 + 1] * NLOG2E;
    const float wi10 = w_ih[row1 * 2 + 0] * TLOG2E;
    const float wi11 = w_ih[row1 * 2 + 1] * TLOG2E;
    const float bias0 = (b_ih[row0] + b_hh[row0]) * NLOG2E; // r/z: both biases
    const float bi1   = b_ih[row1] * TLOG2E;                // n: outside r*(...)
    const float bh1   = b_hh[row1] * TLOG2E;                // n: inside r*(...)

    float h_el = 0.0f;            // lane's copy of h[low]
    float hs[32];                 // wave-uniform h (SGPR-resident)
#pragma unroll
    for (int j = 0; j < 32; ++j) hs[j] = 0.0f;

    // x[t, 255, 0:2] as float2 at index t*256+255; 64 steps per lane-load,
    // prefetched one block ahead.
    const float2* xp = (const float2*)x;
    float2 xv = xp[(size_t)lane * 256 + 255];
    float hacc[4];

    for (int tb = 0; tb < 64; ++tb) {
        float2 xv_next = xv;
        if (tb < 63) xv_next = xp[((size_t)(tb + 1) * 64 + lane) * 256 + 255];
        // transposed layout: hbuf[j*TT + t], t = tb*64 + i
        float4* hout = (float4*)(hbuf + (size_t)low * TT + tb * 64);

#pragma unroll 4
        for (int i = 0; i < 64; ++i) {
            const float x0 = rl(xv.x, i);          // uniform lane idx i
            const float x1 = rl(xv.y, i);
            float a = fmaf(x1, wi01, fmaf(x0, wi00, bias0));  // scaled r/z pre
            float b = 0.f, c = 0.f, d = 0.f;
            const float xn = fmaf(x1, wi11, fmaf(x0, wi10, bi1));
            float n0 = bh1, n1 = 0.f, n2 = 0.f, n3 = 0.f;

            // dots: hs[j] are SGPRs -> v_fma with SGPR src, 4-way chains
#pragma unroll
            for (int j = 0; j < 32; j += 4) {
                a  = fmaf(hs[j + 0], w0a[j + 0], a);
                b  = fmaf(hs[j + 1], w0a[j + 1], b);
                c  = fmaf(hs[j + 2], w0a[j + 2], c);
                d  = fmaf(hs[j + 3], w0a[j + 3], d);
                n0 = fmaf(hs[j + 0], w1a[j + 0], n0);
                n1 = fmaf(hs[j + 1], w1a[j + 1], n1);
                n2 = fmaf(hs[j + 2], w1a[j + 2], n2);
                n3 = fmaf(hs[j + 3], w1a[j + 3], n3);
            }
            const float pre_s = (a + b) + (c + d);    // -log2e * (r/z pre)
            const float hn_s  = (n0 + n1) + (n2 + n3);// 2log2e * (b_hh + h.w_n)

            const float sg    = frcp(1.0f + fexp2(pre_s));  // sigmoid
            const float other = __shfl_xor(sg, 32);          // known-good swap
            const float rr = hi ? other : sg;
            const float zz = hi ? sg : other;

            // n = tanh(xn + r*hn), arg pre-scaled by 2log2e
            const float nv = fmaf(-2.0f, frcp(1.0f + fexp2(fmaf(rr, hn_s, xn))), 1.0f);
            h_el = fmaf(zz, h_el - nv, nv);           // h = n + z*(h-n)

            hacc[i & 3] = h_el;
            if ((i & 3) == 3) hout[i >> 2] = *(const float4*)hacc;

            // broadcast new h to SGPRs for next step
#pragma unroll
            for (int j = 0; j < 32; ++j) hs[j] = rl(h_el, j);
        }
        xv = xv_next;
    }
}

// out[t] = sum_j hbuf[j*TT + t] * w_fc[j] + b_fc   (transposed hbuf)
__global__ void fc_out(const float* __restrict__ hbuf,
                       const float* __restrict__ w_fc,
                       const float* __restrict__ b_fc,
                       float* __restrict__ out)
{
    const int t = blockIdx.x * blockDim.x + threadIdx.x;
    if (t >= TT) return;
    float acc = 0.f;
#pragma unroll
    for (int j = 0; j < 32; ++j) acc = fmaf(hbuf[j * TT + t], w_fc[j], acc);
    out[t] = acc + b_fc[0];
}

extern "C" void kernel_launch(void* const* d_in, const int* in_sizes, int n_in,
                              void* d_out, int out_size, void* d_ws, size_t ws_size,
                              hipStream_t stream) {
    const float* x    = (const float*)d_in[0];
    const float* w_ih = (const float*)d_in[1];
    const float* w_hh = (const float*)d_in[2];
    const float* b_ih = (const float*)d_in[3];
    const float* b_hh = (const float*)d_in[4];
    const float* w_fc = (const float*)d_in[5];
    const float* b_fc = (const float*)d_in[6];
    float* out  = (float*)d_out;
    float* hbuf = (float*)d_ws;   // 32*TT*4 = 512 KB

    gru_seq<<<1, 64, 0, stream>>>(x, w_ih, w_hh, b_ih, b_hh, hbuf);
    fc_out<<<TT / 256, 256, 0, stream>>>(hbuf, w_fc, b_fc, out);
}

// Round 7
// 776.778 us; speedup vs baseline: 1.1331x; 1.1331x over previous
//
#include <hip/hip_runtime.h>

// GRU, T=4096, B=256, I=2, H=32, O=1.
// Only batch row 255 reaches the output -> compute only that row.
// Single-wave sequential recurrence; issue/latency-bound.
// R7 = R6 with the cvt_pkrtz type plumbing fixed (bit_cast instead of the
//     mismatched union overload). Theory unchanged:
//     fp16 weights + v_dot2_f32_f16 -> weight set = 32 VGPRs, fits the
//     64-reg budget (R2/R3/R5: VGPR=64, weights spilled/reloaded in-loop).
//     h broadcast = 16 readlanes of packed fp16 pairs (DPP xor-1 pack).
//     fp32 math elsewhere; z-exchange via known-good __shfl_xor(32).

#define TT 4096

typedef _Float16 h2 __attribute__((ext_vector_type(2)));

__device__ __forceinline__ float rl(float v, int l) {
    return __int_as_float(__builtin_amdgcn_readlane(__float_as_int(v), l));
}
__device__ __forceinline__ int rli(int v, int l) {
    return __builtin_amdgcn_readlane(v, l);
}
__device__ __forceinline__ float fexp2(float x) { return __builtin_amdgcn_exp2f(x); }
__device__ __forceinline__ float frcp(float x)  { return __builtin_amdgcn_rcpf(x); }
__device__ __forceinline__ h2 asph(int v) { return __builtin_bit_cast(h2, v); }

#define NLOG2E  (-1.44269504088896340736f)   // r/z pre-activations pre-scaled
#define TLOG2E  ( 2.88539008177792681472f)   // n pre-activation pre-scaled

// One wave. Lane l owns w_hh gate-row l (r rows lanes 0..31, z rows lanes
// 32..63) and n-row 64+(l&31) (duplicated across halves -> both halves hold
// bitwise-identical h). h broadcast as 16 packed fp16 pairs via readlane.
__global__ __launch_bounds__(64, 1)
void gru_seq(const float* __restrict__ x,
             const float* __restrict__ w_ih,
             const float* __restrict__ w_hh,
             const float* __restrict__ b_ih,
             const float* __restrict__ b_hh,
             float* __restrict__ hbuf)
{
    const int lane = threadIdx.x;
    const int low  = lane & 31;
    const bool hi  = lane >= 32;
    const int row0 = lane;        // r/z row
    const int row1 = 64 + low;    // n row (both halves)

    // fp16 weights, exp2 scales folded: 16+16 VGPRs total.
    h2 w0p[16], w1p[16];
#pragma unroll
    for (int m = 0; m < 16; ++m) {
        float a = w_hh[row0 * 32 + 2 * m] * NLOG2E;
        float b = w_hh[row0 * 32 + 2 * m + 1] * NLOG2E;
        w0p[m] = h2{(_Float16)a, (_Float16)b};
    }
#pragma unroll
    for (int m = 0; m < 16; ++m) {
        float a = w_hh[row1 * 32 + 2 * m] * TLOG2E;
        float b = w_hh[row1 * 32 + 2 * m + 1] * TLOG2E;
        w1p[m] = h2{(_Float16)a, (_Float16)b};
    }

    const float wi00 = w_ih[row0 * 2 + 0] * NLOG2E;
    const float wi01 = w_ih[row0 * 2 + 1] * NLOG2E;
    const float wi10 = w_ih[row1 * 2 + 0] * TLOG2E;
    const float wi11 = w_ih[row1 * 2 + 1] * TLOG2E;
    const float bias0 = (b_ih[row0] + b_hh[row0]) * NLOG2E; // r/z: both biases
    const float bi1   = b_ih[row1] * TLOG2E;                // n: outside r*(...)
    const float bh1   = b_hh[row1] * TLOG2E;                // n: inside r*(...)

    float h_el = 0.0f;            // lane's copy of h[low], fp32
    int hsp[16];                  // wave-uniform packed fp16 h pairs
#pragma unroll
    for (int m = 0; m < 16; ++m) hsp[m] = 0;

    // x[t, 255, 0:2] as float2 at index t*256+255; 64 steps per lane-load,
    // prefetched one block ahead.
    const float2* xp = (const float2*)x;
    float2 xv = xp[(size_t)lane * 256 + 255];
    float hacc[4];
    const int odd = lane & 1;

    for (int tb = 0; tb < 64; ++tb) {
        float2 xv_next = xv;
        if (tb < 63) xv_next = xp[((size_t)(tb + 1) * 64 + lane) * 256 + 255];
        // transposed layout: hbuf[j*TT + t], t = tb*64 + i
        float4* hout = (float4*)(hbuf + (size_t)low * TT + tb * 64);

#pragma unroll 4
        for (int i = 0; i < 64; ++i) {
            const float x0 = rl(xv.x, i);          // uniform lane idx i
            const float x1 = rl(xv.y, i);
            const float base0 = fmaf(x1, wi01, fmaf(x0, wi00, bias0));
            const float xn    = fmaf(x1, wi11, fmaf(x0, wi10, bi1));

            // dots via v_dot2_f32_f16, 2 accumulator chains per gate
            float a0 = base0, a1 = 0.f;
            float n0 = bh1,   n1 = 0.f;
#pragma unroll
            for (int m = 0; m < 16; m += 2) {
                const h2 hA = asph(hsp[m]);
                const h2 hB = asph(hsp[m + 1]);
                a0 = __builtin_amdgcn_fdot2(w0p[m],     hA, a0, false);
                a1 = __builtin_amdgcn_fdot2(w0p[m + 1], hB, a1, false);
                n0 = __builtin_amdgcn_fdot2(w1p[m],     hA, n0, false);
                n1 = __builtin_amdgcn_fdot2(w1p[m + 1], hB, n1, false);
            }
            const float pre_s = a0 + a1;           // -log2e * (r/z pre)
            const float hn_s  = n0 + n1;           // 2log2e * (b_hh + h.w_n)

            const float sg    = frcp(1.0f + fexp2(pre_s));  // sigmoid
            const float other = __shfl_xor(sg, 32);          // known-good swap
            const float rr = hi ? other : sg;
            const float zz = hi ? sg : other;

            // n = tanh(xn + r*hn), arg pre-scaled by 2log2e
            const float nv = fmaf(-2.0f, frcp(1.0f + fexp2(fmaf(rr, hn_s, xn))), 1.0f);
            h_el = fmaf(zz, h_el - nv, nv);        // h = n + z*(h-n)

            hacc[i & 3] = h_el;
            if ((i & 3) == 3) hout[i >> 2] = *(const float4*)hacc;

            // producer-side pair pack: neighbor via DPP quad_perm [1,0,3,2]
            const float nb = __int_as_float(__builtin_amdgcn_update_dpp(
                0, __float_as_int(h_el), 0xB1, 0xF, 0xF, true));
            const float pa = odd ? nb : h_el;      // h[2m]
            const float pb = odd ? h_el : nb;      // h[2m+1]
            const int pk = __builtin_bit_cast(int, __builtin_amdgcn_cvt_pkrtz(pa, pb));
            // broadcast 16 pairs from even lanes 0,2,..,30
#pragma unroll
            for (int m = 0; m < 16; ++m) hsp[m] = rli(pk, 2 * m);
        }
        xv = xv_next;
    }
}

// out[t] = sum_j hbuf[j*TT + t] * w_fc[j] + b_fc   (transposed hbuf)
__global__ void fc_out(const float* __restrict__ hbuf,
                       const float* __restrict__ w_fc,
                       const float* __restrict__ b_fc,
                       float* __restrict__ out)
{
    const int t = blockIdx.x * blockDim.x + threadIdx.x;
    if (t >= TT) return;
    float acc = 0.f;
#pragma unroll
    for (int j = 0; j < 32; ++j) acc = fmaf(hbuf[j * TT + t], w_fc[j], acc);
    out[t] = acc + b_fc[0];
}

extern "C" void kernel_launch(void* const* d_in, const int* in_sizes, int n_in,
                              void* d_out, int out_size, void* d_ws, size_t ws_size,
                              hipStream_t stream) {
    const float* x    = (const float*)d_in[0];
    const float* w_ih = (const float*)d_in[1];
    const float* w_hh = (const float*)d_in[2];
    const float* b_ih = (const float*)d_in[3];
    const float* b_hh = (const float*)d_in[4];
    const float* w_fc = (const float*)d_in[5];
    const float* b_fc = (const float*)d_in[6];
    float* out  = (float*)d_out;
    float* hbuf = (float*)d_ws;   // 32*TT*4 = 512 KB

    gru_seq<<<1, 64, 0, stream>>>(x, w_ih, w_hh, b_ih, b_hh, hbuf);
    fc_out<<<TT / 256, 256, 0, stream>>>(hbuf, w_fc, b_fc, out);
}